// Round 3
// baseline (454.699 us; speedup 1.0000x reference)
//
#include <hip/hip_runtime.h>
#include <hip/hip_cooperative_groups.h>
#include <math.h>

namespace cg = cooperative_groups;

// ---- Problem constants ----
#define B_    128
#define L_    512
#define H_    128
#define NPT_  1023
#define N_    (B_ * NPT_)     // 130944
#define NLEAF (B_ * L_)       // 65536
#define OUT_  128
#define VOCAB 32000
#define TBASE 960             // first tail node (cnt=32 level base)
#define BROW  264             // padded LDS B-row (256+8 shorts): 2-way = free

typedef unsigned short ushort_t;
typedef __attribute__((ext_vector_type(8))) __bf16 bf16x8;
typedef __attribute__((ext_vector_type(4))) float f32x4;

__device__ __forceinline__ float sigmoidf_(float x) {
    return 1.0f / (1.0f + __expf(-x));
}
__device__ __forceinline__ float tanhf_(float x) {
    return 1.0f - 2.0f / (__expf(2.0f * x) + 1.0f);
}
__device__ __forceinline__ ushort_t f2bf(float f) {
    unsigned u = __float_as_uint(f);
    return (ushort_t)((u + 0x7fffu + ((u >> 16) & 1u)) >> 16);
}
__device__ __forceinline__ float bf2f(ushort_t s) {
    return __uint_as_float(((unsigned)s) << 16);
}

// =====================================================================
// Prep (fused): weights -> bf16 transposed, emb -> bf16.
// =====================================================================
__global__ __launch_bounds__(256)
void prep_fused(const float* __restrict__ W_iou,
                const float* __restrict__ U_iou,
                const float* __restrict__ U_f_w,
                const float* __restrict__ emb,
                ushort_t* __restrict__ W_iouT,     // [384][128]
                ushort_t* __restrict__ U_catT,     // [640][256]
                ushort_t* __restrict__ embb) {     // [VOCAB][128]
    int idx = blockIdx.x * 256 + threadIdx.x;
    if (idx < VOCAB * H_ / 8) {
        int e0 = idx * 8;
        f32x4 f0 = *(const f32x4*)(emb + e0);
        f32x4 f1 = *(const f32x4*)(emb + e0 + 4);
        union { bf16x8 v; ushort_t e[8]; } p;
        p.e[0] = f2bf(f0[0]); p.e[1] = f2bf(f0[1]);
        p.e[2] = f2bf(f0[2]); p.e[3] = f2bf(f0[3]);
        p.e[4] = f2bf(f1[0]); p.e[5] = f2bf(f1[1]);
        p.e[6] = f2bf(f1[2]); p.e[7] = f2bf(f1[3]);
        *(bf16x8*)(embb + e0) = p.v;
    }
    if (idx < 640 * 256) {
        int n = idx >> 8, k = idx & 255;
        float v = (n < 384) ? U_iou[k * 384 + n] : U_f_w[k * 256 + (n - 384)];
        U_catT[idx] = f2bf(v);
    }
    if (idx < 384 * 128) {
        int n = idx >> 7, k = idx & 127;
        W_iouT[idx] = f2bf(W_iou[k * 384 + n]);
    }
}

// =====================================================================
// Leaf (B register-resident, labels preloaded) — r13-verified; c f32.
// =====================================================================
__global__ __launch_bounds__(256, 4)
void leaf_v3(const int* __restrict__ label,
             const ushort_t* __restrict__ embb,
             const ushort_t* __restrict__ WT,
             const float* __restrict__ b_iou,
             ushort_t* __restrict__ h,
             float* __restrict__ c) {
    const int tid  = threadIdx.x;
    const int lane = tid & 63;
    const int wave = tid >> 6;
    const int li   = lane & 15;
    const int q    = lane >> 4;
    const int q8   = q << 3;
    const int gg   = blockIdx.y * 4 + wave;
    const int j    = gg * 16 + li;

    bf16x8 Bf[3][4];
    #pragma unroll
    for (int t = 0; t < 3; ++t) {
        const ushort_t* bp = WT + (size_t)(16 * (gg + 8 * t) + li) * 128 + q8;
        #pragma unroll
        for (int kt = 0; kt < 4; ++kt) Bf[t][kt] = *(const bf16x8*)(bp + kt * 32);
    }

    int lab[8];
    #pragma unroll
    for (int t = 0; t < 8; ++t) {
        int ia = (blockIdx.x + t * 512) * 16 + li;
        int ba = ia >> 9, pa = ia & 511;
        lab[t] = label[ba * NPT_ + pa];
    }

    const float bi = b_iou[j], bo = b_iou[128 + j], bu = b_iou[256 + j];

    #pragma unroll 1
    for (int t8 = 0; t8 < 8; ++t8) {
        const int tile = blockIdx.x + t8 * 512;
        const int i0 = tile * 16;
        const ushort_t* pA = embb + (size_t)lab[t8] * H_;
        bf16x8 a[4];
        #pragma unroll
        for (int kt = 0; kt < 4; ++kt) a[kt] = *(const bf16x8*)(pA + kt * 32 + q8);

        f32x4 acc[3];
        #pragma unroll
        for (int t = 0; t < 3; ++t) acc[t] = (f32x4){0.f, 0.f, 0.f, 0.f};
        #pragma unroll
        for (int kt = 0; kt < 4; ++kt)
            #pragma unroll
            for (int t = 0; t < 3; ++t)
                acc[t] = __builtin_amdgcn_mfma_f32_16x16x32_bf16(a[kt], Bf[t][kt], acc[t], 0, 0, 0);

        #pragma unroll
        for (int r = 0; r < 4; ++r) {
            int m  = i0 + q * 4 + r;
            int b  = m >> 9, pos = m & 511;
            size_t gn = (size_t)(b * NPT_ + pos) * H_ + j;
            float iv = sigmoidf_(acc[0][r] + bi);
            float ov = sigmoidf_(acc[1][r] + bo);
            float uv = tanhf_(acc[2][r] + bu);
            float cv = iv * uv;
            float hv = ov * tanhf_(cv);
            c[gn] = cv;
            h[gn] = f2bf(hv);
        }
    }
}

// =====================================================================
// FUSED levels (cooperative): cnt = 256,128,64 in ONE kernel.
// 512 blocks x 256 thr; gg = bid>>6 (8 gg-blocks of a stripe share an
// XCD since 64 % 8 == 0); B staged to LDS ONCE, reused for all 3
// levels; grid.sync() + __threadfence() between levels (G16).
// Co-residency: LDS 42.2KB -> 3 blk/CU; VGPR<256 -> 2 blk/CU; 512 fit.
// Tile body byte-identical to r13-verified level_lds.
// =====================================================================
__global__ __launch_bounds__(256, 2)
void levels_fused(const ushort_t* __restrict__ Ucat,
                  const float* __restrict__ b_iou,
                  const float* __restrict__ U_f_b,
                  ushort_t* __restrict__ h,
                  float* __restrict__ c) {
    __shared__ ushort_t Bs[5 * 16 * BROW];          // 42.2 KB
    cg::grid_group grid = cg::this_grid();

    const int tid  = threadIdx.x;
    const int lane = tid & 63;
    const int wave = tid >> 6;
    const int li   = lane & 15;
    const int q    = lane >> 4;
    const int q8   = q << 3;
    const int gg   = blockIdx.x >> 6;               // gate group 0..7
    const int sid  = blockIdx.x & 63;               // stripe 0..63
    const int j    = gg * 16 + li;

    // ---- stage B once: 80 rows x 256 shorts ----
    #pragma unroll
    for (int it = 0; it < 5; ++it) {
        int chunk = tid + it * 256;                 // 0..1279
        int row = chunk >> 4, seg = chunk & 15;
        int t = row >> 4, lr = row & 15;
        const ushort_t* src = Ucat + (size_t)(16 * (gg + 8 * t) + lr) * 256 + seg * 16;
        ushort_t*       dst = Bs + (t * 16 + lr) * BROW + seg * 16;
        *(f32x4*)(dst)     = *(const f32x4*)(src);
        *(f32x4*)(dst + 8) = *(const f32x4*)(src + 8);
    }
    __syncthreads();

    const float bi  = b_iou[j], bo = b_iou[128 + j], bu = b_iou[256 + j];
    const float bfl = U_f_b[j], bfr = U_f_b[128 + j];

    int child = 0, node = 512, cnt = 256, lc = 8;
    #pragma unroll 1
    for (int lvl = 0; lvl < 3; ++lvl) {
        const int mask   = (1 << lc) - 1;
        const int ntiles = (B_ * cnt) >> 4;

        #pragma unroll 1
        for (int tile = sid * 4 + wave; tile < ntiles; tile += 256) {
            const int i0 = tile * 16;

            // epilogue c-children prefetch (independent; hides under K-loop)
            float clv[4], crv[4];
            int   gnrow[4];
            #pragma unroll
            for (int r = 0; r < 4; ++r) {
                int m = i0 + q * 4 + r;
                int b = m >> lc, pos = m & mask;
                int gl = b * NPT_ + child + 2 * pos;
                gnrow[r] = b * NPT_ + node + pos;
                clv[r] = c[(size_t)gl * H_ + j];
                crv[r] = c[(size_t)(gl + 1) * H_ + j];
            }

            // A: 16 h_cat rows; kt<4 left child, kt>=4 right child
            int ia = i0 + li, ba = ia >> lc, pa = ia & mask;
            int gl0 = ba * NPT_ + child + 2 * pa;
            const ushort_t* pl = h + (size_t)gl0 * H_;
            const ushort_t* pr = h + (size_t)(gl0 + 1) * H_;
            bf16x8 a[8];
            #pragma unroll
            for (int kt = 0; kt < 8; ++kt) {
                const ushort_t* p = (kt < 4) ? pl : pr;
                a[kt] = *(const bf16x8*)(p + (kt & 3) * 32 + q8);
            }

            f32x4 acc[5];
            #pragma unroll
            for (int t = 0; t < 5; ++t) acc[t] = (f32x4){0.f, 0.f, 0.f, 0.f};
            #pragma unroll
            for (int kt = 0; kt < 8; ++kt) {
                #pragma unroll
                for (int t = 0; t < 5; ++t) {
                    bf16x8 bf = *(const bf16x8*)(Bs + (t * 16 + li) * BROW + kt * 32 + q8);
                    acc[t] = __builtin_amdgcn_mfma_f32_16x16x32_bf16(a[kt], bf, acc[t], 0, 0, 0);
                }
            }

            #pragma unroll
            for (int r = 0; r < 4; ++r) {
                size_t gn = (size_t)gnrow[r] * H_ + j;
                float iv = sigmoidf_(acc[0][r] + bi);
                float ov = sigmoidf_(acc[1][r] + bo);
                float uv = tanhf_(acc[2][r] + bu);
                float fl = sigmoidf_(acc[3][r] + bfl);
                float fr = sigmoidf_(acc[4][r] + bfr);
                float cv = iv * uv + fl * clv[r] + fr * crv[r];
                float hv = ov * tanhf_(cv);
                c[gn] = cv;
                h[gn] = f2bf(hv);
            }
        }

        if (lvl != 2) {
            __threadfence();                        // device-scope release (cross-XCD)
            grid.sync();
        }
        child = node; node += cnt; cnt >>= 1; --lc;
    }
}

// =====================================================================
// Tail — r13-verified: one block (8 waves = 8 gate groups) per TREE.
// Levels cnt=32..1 + root; tail h/c in LDS (63 nodes); c f32.
// Output head: 4-way K-parallel dot product across all 512 threads.
// =====================================================================
#define TPAD 132
__global__ __launch_bounds__(512, 2)
void tail_kernel(const ushort_t* __restrict__ Ucat,
                 const float* __restrict__ b_iou,
                 const float* __restrict__ U_f_b,
                 const ushort_t* __restrict__ h,
                 const float* __restrict__ c,
                 const float* __restrict__ W_out,
                 const float* __restrict__ b_out,
                 float* __restrict__ out) {
    __shared__ ushort_t hl[63][TPAD];
    __shared__ float    cl[63][TPAD];
    __shared__ float    ev[H_];
    __shared__ float    red[128];
    __shared__ float    red4[4][128];

    const int tid  = threadIdx.x;
    const int lane = tid & 63;
    const int wave = tid >> 6;
    const int li   = lane & 15;
    const int q    = lane >> 4;
    const int q8   = q << 3;
    const int gg   = wave;
    const int j    = gg * 16 + li;
    const int b    = blockIdx.x;

    bf16x8 Bf[5][8];
    #pragma unroll
    for (int t = 0; t < 5; ++t) {
        const ushort_t* bp = Ucat + (size_t)(16 * (gg + 8 * t) + li) * 256 + q8;
        #pragma unroll
        for (int kt = 0; kt < 8; ++kt) Bf[t][kt] = *(const bf16x8*)(bp + kt * 32);
    }

    const float bi  = b_iou[j], bo = b_iou[128 + j], bu = b_iou[256 + j];
    const float bfl = U_f_b[j], bfr = U_f_b[128 + j];

    int base = TBASE, child = 896, cnt = 32;
    #pragma unroll 1
    for (int lvl = 0; lvl < 6; ++lvl) {
        const int tiles = (cnt + 15) >> 4;
        for (int tile = 0; tile < tiles; ++tile) {
            const int i0 = tile * 16;

            int pos = i0 + li; if (pos >= cnt) pos = cnt - 1;
            bf16x8 a[8];
            if (lvl == 0) {
                int gl0 = b * NPT_ + child + 2 * pos;
                const ushort_t* pl = h + (size_t)gl0 * H_;
                const ushort_t* pr = h + (size_t)(gl0 + 1) * H_;
                #pragma unroll
                for (int kt = 0; kt < 8; ++kt) {
                    const ushort_t* p = (kt < 4) ? pl : pr;
                    a[kt] = *(const bf16x8*)(p + (kt & 3) * 32 + q8);
                }
            } else {
                int tl = (child - TBASE) + 2 * pos;
                #pragma unroll
                for (int kt = 0; kt < 8; ++kt) {
                    const ushort_t* p = (kt < 4) ? hl[tl] : hl[tl + 1];
                    a[kt] = *(const bf16x8*)(p + (kt & 3) * 32 + q8);
                }
            }

            float clv[4], crv[4];
            #pragma unroll
            for (int r = 0; r < 4; ++r) {
                int m  = i0 + q * 4 + r;
                int pm = m < cnt ? m : cnt - 1;
                if (lvl == 0) {
                    int gl = b * NPT_ + child + 2 * pm;
                    clv[r] = c[(size_t)gl * H_ + j];
                    crv[r] = c[(size_t)(gl + 1) * H_ + j];
                } else {
                    int tl = (child - TBASE) + 2 * pm;
                    clv[r] = cl[tl][j];
                    crv[r] = cl[tl + 1][j];
                }
            }

            f32x4 acc[5];
            #pragma unroll
            for (int t = 0; t < 5; ++t) acc[t] = (f32x4){0.f, 0.f, 0.f, 0.f};
            #pragma unroll
            for (int kt = 0; kt < 8; ++kt)
                #pragma unroll
                for (int t = 0; t < 5; ++t)
                    acc[t] = __builtin_amdgcn_mfma_f32_16x16x32_bf16(a[kt], Bf[t][kt], acc[t], 0, 0, 0);

            #pragma unroll
            for (int r = 0; r < 4; ++r) {
                int m = i0 + q * 4 + r;
                if (m < cnt) {
                    int tl = (base - TBASE) + m;
                    float iv = sigmoidf_(acc[0][r] + bi);
                    float ov = sigmoidf_(acc[1][r] + bo);
                    float uv = tanhf_(acc[2][r] + bu);
                    float fl = sigmoidf_(acc[3][r] + bfl);
                    float fr = sigmoidf_(acc[4][r] + bfr);
                    float cv = iv * uv + fl * clv[r] + fr * crv[r];
                    float hv = ov * tanhf_(cv);
                    cl[tl][j] = cv;
                    hl[tl][j] = f2bf(hv);
                }
            }
        }
        __syncthreads();
        child = base; base += cnt; cnt >>= 1;
    }

    if (tid < 128) ev[tid] = bf2f(hl[62][tid]);
    __syncthreads();

    // ---- output head: out[o] = b_out[o] + sum_k ev[k]*W_out[k][o] ----
    {
        const int o  = tid & 127;
        const int kc = tid >> 7;            // 0..3 -> k in [kc*32, kc*32+32)
        float pacc = (kc == 0) ? b_out[o] : 0.0f;
        #pragma unroll 8
        for (int k = kc * 32; k < kc * 32 + 32; ++k)
            pacc += ev[k] * W_out[k * OUT_ + o];
        red4[kc][o] = pacc;
    }
    __syncthreads();

    float acc = 0.0f;
    if (tid < 128) {
        acc = red4[0][tid] + red4[1][tid] + red4[2][tid] + red4[3][tid];
        red[tid] = acc;
    }
    __syncthreads();
    for (int s = 64; s > 0; s >>= 1) {
        if (tid < s) red[tid] = fmaxf(red[tid], red[tid + s]);
        __syncthreads();
    }
    float mx = red[0];
    __syncthreads();
    if (tid < 128) red[tid] = expf(acc - mx);
    __syncthreads();
    for (int s = 64; s > 0; s >>= 1) {
        if (tid < s) red[tid] += red[tid + s];
        __syncthreads();
    }
    float lse = logf(red[0]);
    if (tid < 128) out[b * OUT_ + tid] = acc - mx - lse;
}

// =====================================================================
extern "C" void kernel_launch(void* const* d_in, const int* in_sizes, int n_in,
                              void* d_out, int out_size, void* d_ws, size_t ws_size,
                              hipStream_t stream) {
    const int*   label = (const int*)d_in[0];
    const float* emb   = (const float*)d_in[1];
    const float* W_iou = (const float*)d_in[2];
    const float* U_iou = (const float*)d_in[3];
    const float* b_iou = (const float*)d_in[4];
    const float* U_f_w = (const float*)d_in[5];
    const float* U_f_b = (const float*)d_in[6];
    const float* W_out = (const float*)d_in[7];
    const float* b_out = (const float*)d_in[8];
    float* outp = (float*)d_out;

    // ws layout: c f32 | h bf16 | Ucat | WT | embb
    float*    c    = (float*)d_ws;
    ushort_t* h    = (ushort_t*)(c + (size_t)N_ * H_);
    ushort_t* Ucat = h + (size_t)N_ * H_;
    ushort_t* WT   = Ucat + 640 * 256;
    ushort_t* embb = WT + 384 * 128;

    prep_fused<<<2000, 256, 0, stream>>>(W_iou, U_iou, U_f_w, emb, WT, Ucat, embb);

    // leaf: 4096 M-tiles of 16; 512 stripes x 2 group-halves; 8 tiles/wave
    leaf_v3<<<dim3(512, 2), 256, 0, stream>>>(label, embb, WT, b_iou, h, c);

    // fused levels: cnt = 256,128,64 — one cooperative kernel, 512 blocks
    {
        void* kargs[] = { (void*)&Ucat, (void*)&b_iou, (void*)&U_f_b,
                          (void*)&h, (void*)&c };
        hipLaunchCooperativeKernel((const void*)levels_fused,
                                   dim3(512), dim3(256), kargs, 0, stream);
    }

    // tail: cnt=32..1 + root, one block per tree
    tail_kernel<<<B_, 512, 0, stream>>>(Ucat, b_iou, U_f_b, h, c, W_out, b_out, outp);
}

// Round 5
// 278.819 us; speedup vs baseline: 1.6308x; 1.6308x over previous
//
#include <hip/hip_runtime.h>
#include <math.h>

// ---- Problem constants ----
#define B_    128
#define L_    512
#define H_    128
#define NPT_  1023
#define N_    (B_ * NPT_)     // 130944
#define NLEAF (B_ * L_)       // 65536
#define OUT_  128
#define VOCAB 32000
#define TBASE 960             // first tail node (cnt=32 level base)
#define BROW  264             // padded LDS B-row (256+8 shorts): 2-way = free

typedef unsigned short ushort_t;
typedef __attribute__((ext_vector_type(8))) __bf16 bf16x8;
typedef __attribute__((ext_vector_type(4))) float f32x4;

__device__ __forceinline__ float sigmoidf_(float x) {
    return 1.0f / (1.0f + __expf(-x));
}
__device__ __forceinline__ float tanhf_(float x) {
    return 1.0f - 2.0f / (__expf(2.0f * x) + 1.0f);
}
__device__ __forceinline__ ushort_t f2bf(float f) {
    unsigned u = __float_as_uint(f);
    return (ushort_t)((u + 0x7fffu + ((u >> 16) & 1u)) >> 16);
}
__device__ __forceinline__ float bf2f(ushort_t s) {
    return __uint_as_float(((unsigned)s) << 16);
}

// =====================================================================
// Prep (fused): weights -> bf16 transposed, emb -> bf16.
// =====================================================================
__global__ __launch_bounds__(256)
void prep_fused(const float* __restrict__ W_iou,
                const float* __restrict__ U_iou,
                const float* __restrict__ U_f_w,
                const float* __restrict__ emb,
                ushort_t* __restrict__ W_iouT,     // [384][128]
                ushort_t* __restrict__ U_catT,     // [640][256]
                ushort_t* __restrict__ embb) {     // [VOCAB][128]
    int idx = blockIdx.x * 256 + threadIdx.x;
    if (idx < VOCAB * H_ / 8) {
        int e0 = idx * 8;
        f32x4 f0 = *(const f32x4*)(emb + e0);
        f32x4 f1 = *(const f32x4*)(emb + e0 + 4);
        union { bf16x8 v; ushort_t e[8]; } p;
        p.e[0] = f2bf(f0[0]); p.e[1] = f2bf(f0[1]);
        p.e[2] = f2bf(f0[2]); p.e[3] = f2bf(f0[3]);
        p.e[4] = f2bf(f1[0]); p.e[5] = f2bf(f1[1]);
        p.e[6] = f2bf(f1[2]); p.e[7] = f2bf(f1[3]);
        *(bf16x8*)(embb + e0) = p.v;
    }
    if (idx < 640 * 256) {
        int n = idx >> 8, k = idx & 255;
        float v = (n < 384) ? U_iou[k * 384 + n] : U_f_w[k * 256 + (n - 384)];
        U_catT[idx] = f2bf(v);
    }
    if (idx < 384 * 128) {
        int n = idx >> 7, k = idx & 127;
        W_iouT[idx] = f2bf(W_iou[k * 384 + n]);
    }
}

// =====================================================================
// Leaf (B register-resident, labels preloaded) — r13-verified; c f32.
// =====================================================================
__global__ __launch_bounds__(256, 4)
void leaf_v3(const int* __restrict__ label,
             const ushort_t* __restrict__ embb,
             const ushort_t* __restrict__ WT,
             const float* __restrict__ b_iou,
             ushort_t* __restrict__ h,
             float* __restrict__ c) {
    const int tid  = threadIdx.x;
    const int lane = tid & 63;
    const int wave = tid >> 6;
    const int li   = lane & 15;
    const int q    = lane >> 4;
    const int q8   = q << 3;
    const int gg   = blockIdx.y * 4 + wave;
    const int j    = gg * 16 + li;

    bf16x8 Bf[3][4];
    #pragma unroll
    for (int t = 0; t < 3; ++t) {
        const ushort_t* bp = WT + (size_t)(16 * (gg + 8 * t) + li) * 128 + q8;
        #pragma unroll
        for (int kt = 0; kt < 4; ++kt) Bf[t][kt] = *(const bf16x8*)(bp + kt * 32);
    }

    int lab[8];
    #pragma unroll
    for (int t = 0; t < 8; ++t) {
        int ia = (blockIdx.x + t * 512) * 16 + li;
        int ba = ia >> 9, pa = ia & 511;
        lab[t] = label[ba * NPT_ + pa];
    }

    const float bi = b_iou[j], bo = b_iou[128 + j], bu = b_iou[256 + j];

    #pragma unroll 1
    for (int t8 = 0; t8 < 8; ++t8) {
        const int tile = blockIdx.x + t8 * 512;
        const int i0 = tile * 16;
        const ushort_t* pA = embb + (size_t)lab[t8] * H_;
        bf16x8 a[4];
        #pragma unroll
        for (int kt = 0; kt < 4; ++kt) a[kt] = *(const bf16x8*)(pA + kt * 32 + q8);

        f32x4 acc[3];
        #pragma unroll
        for (int t = 0; t < 3; ++t) acc[t] = (f32x4){0.f, 0.f, 0.f, 0.f};
        #pragma unroll
        for (int kt = 0; kt < 4; ++kt)
            #pragma unroll
            for (int t = 0; t < 3; ++t)
                acc[t] = __builtin_amdgcn_mfma_f32_16x16x32_bf16(a[kt], Bf[t][kt], acc[t], 0, 0, 0);

        #pragma unroll
        for (int r = 0; r < 4; ++r) {
            int m  = i0 + q * 4 + r;
            int b  = m >> 9, pos = m & 511;
            size_t gn = (size_t)(b * NPT_ + pos) * H_ + j;
            float iv = sigmoidf_(acc[0][r] + bi);
            float ov = sigmoidf_(acc[1][r] + bo);
            float uv = tanhf_(acc[2][r] + bu);
            float cv = iv * uv;
            float hv = ov * tanhf_(cv);
            c[gn] = cv;
            h[gn] = f2bf(hv);
        }
    }
}

// =====================================================================
// Level, B in LDS, M=16/wave — r13-verified; c f32. Block = 4 waves,
// ONE gate group (blockIdx.y); B slice staged to LDS once (one
// barrier); waves independently run M-tiles of 16.
// r15: latency-bound (MfmaUtil 2.6%, VALU 9%) -> raise TLP:
//   (256,3) = 3 blocks/CU (LDS 3x42.2=127KB ok, VGPR 124 ok),
//   2 tiles/wave (stripes = ntiles/8) = 2x blocks.
// =====================================================================
__global__ __launch_bounds__(256, 3)
void level_lds(const ushort_t* __restrict__ Ucat,
               const float* __restrict__ b_iou,
               const float* __restrict__ U_f_b,
               ushort_t* __restrict__ h,
               float* __restrict__ c,
               int node_base, int child_base, int lc, int ntiles) {
    __shared__ ushort_t Bs[5 * 16 * BROW];          // 42.2 KB
    const int tid  = threadIdx.x;
    const int lane = tid & 63;
    const int wave = tid >> 6;
    const int li   = lane & 15;
    const int q    = lane >> 4;
    const int q8   = q << 3;
    const int mask = (1 << lc) - 1;
    const int gg   = blockIdx.y;                    // gate group
    const int j    = gg * 16 + li;

    // ---- stage B: 80 rows x 256 shorts, coalesced 32B chunks ----
    #pragma unroll
    for (int it = 0; it < 5; ++it) {
        int chunk = tid + it * 256;                 // 0..1279
        int row = chunk >> 4, seg = chunk & 15;
        int t = row >> 4, lr = row & 15;
        const ushort_t* src = Ucat + (size_t)(16 * (gg + 8 * t) + lr) * 256 + seg * 16;
        ushort_t*       dst = Bs + (t * 16 + lr) * BROW + seg * 16;
        *(f32x4*)(dst)     = *(const f32x4*)(src);
        *(f32x4*)(dst + 8) = *(const f32x4*)(src + 8);
    }
    __syncthreads();

    const float bi  = b_iou[j], bo = b_iou[128 + j], bu = b_iou[256 + j];
    const float bfl = U_f_b[j], bfr = U_f_b[128 + j];
    const int wstride = gridDim.x * 4;

    #pragma unroll 1
    for (int tile = blockIdx.x * 4 + wave; tile < ntiles; tile += wstride) {
        const int i0 = tile * 16;

        // epilogue c-children prefetch (independent; hides under K-loop)
        float clv[4], crv[4];
        int   gnrow[4];
        #pragma unroll
        for (int r = 0; r < 4; ++r) {
            int m = i0 + q * 4 + r;
            int b = m >> lc, pos = m & mask;
            int gl = b * NPT_ + child_base + 2 * pos;
            gnrow[r] = b * NPT_ + node_base + pos;
            clv[r] = c[(size_t)gl * H_ + j];
            crv[r] = c[(size_t)(gl + 1) * H_ + j];
        }

        // A: 16 h_cat rows; kt<4 left child, kt>=4 right child
        int ia = i0 + li, ba = ia >> lc, pa = ia & mask;
        int gl0 = ba * NPT_ + child_base + 2 * pa;
        const ushort_t* pl = h + (size_t)gl0 * H_;
        const ushort_t* pr = h + (size_t)(gl0 + 1) * H_;
        bf16x8 a[8];
        #pragma unroll
        for (int kt = 0; kt < 8; ++kt) {
            const ushort_t* p = (kt < 4) ? pl : pr;
            a[kt] = *(const bf16x8*)(p + (kt & 3) * 32 + q8);
        }

        f32x4 acc[5];
        #pragma unroll
        for (int t = 0; t < 5; ++t) acc[t] = (f32x4){0.f, 0.f, 0.f, 0.f};
        #pragma unroll
        for (int kt = 0; kt < 8; ++kt) {
            #pragma unroll
            for (int t = 0; t < 5; ++t) {
                bf16x8 bf = *(const bf16x8*)(Bs + (t * 16 + li) * BROW + kt * 32 + q8);
                acc[t] = __builtin_amdgcn_mfma_f32_16x16x32_bf16(a[kt], bf, acc[t], 0, 0, 0);
            }
        }

        #pragma unroll
        for (int r = 0; r < 4; ++r) {
            size_t gn = (size_t)gnrow[r] * H_ + j;
            float iv = sigmoidf_(acc[0][r] + bi);
            float ov = sigmoidf_(acc[1][r] + bo);
            float uv = tanhf_(acc[2][r] + bu);
            float fl = sigmoidf_(acc[3][r] + bfl);
            float fr = sigmoidf_(acc[4][r] + bfr);
            float cv = iv * uv + fl * clv[r] + fr * crv[r];
            float hv = ov * tanhf_(cv);
            c[gn] = cv;
            h[gn] = f2bf(hv);
        }
    }
}

// =====================================================================
// Tail — r13-verified: one block (8 waves = 8 gate groups) per TREE.
// Levels cnt=32..1 + root; tail h/c in LDS (63 nodes); c f32.
// Output head: 4-way K-parallel dot product across all 512 threads.
// =====================================================================
#define TPAD 132
__global__ __launch_bounds__(512, 2)
void tail_kernel(const ushort_t* __restrict__ Ucat,
                 const float* __restrict__ b_iou,
                 const float* __restrict__ U_f_b,
                 const ushort_t* __restrict__ h,
                 const float* __restrict__ c,
                 const float* __restrict__ W_out,
                 const float* __restrict__ b_out,
                 float* __restrict__ out) {
    __shared__ ushort_t hl[63][TPAD];
    __shared__ float    cl[63][TPAD];
    __shared__ float    ev[H_];
    __shared__ float    red[128];
    __shared__ float    red4[4][128];

    const int tid  = threadIdx.x;
    const int lane = tid & 63;
    const int wave = tid >> 6;
    const int li   = lane & 15;
    const int q    = lane >> 4;
    const int q8   = q << 3;
    const int gg   = wave;
    const int j    = gg * 16 + li;
    const int b    = blockIdx.x;

    bf16x8 Bf[5][8];
    #pragma unroll
    for (int t = 0; t < 5; ++t) {
        const ushort_t* bp = Ucat + (size_t)(16 * (gg + 8 * t) + li) * 256 + q8;
        #pragma unroll
        for (int kt = 0; kt < 8; ++kt) Bf[t][kt] = *(const bf16x8*)(bp + kt * 32);
    }

    const float bi  = b_iou[j], bo = b_iou[128 + j], bu = b_iou[256 + j];
    const float bfl = U_f_b[j], bfr = U_f_b[128 + j];

    int base = TBASE, child = 896, cnt = 32;
    #pragma unroll 1
    for (int lvl = 0; lvl < 6; ++lvl) {
        const int tiles = (cnt + 15) >> 4;
        for (int tile = 0; tile < tiles; ++tile) {
            const int i0 = tile * 16;

            int pos = i0 + li; if (pos >= cnt) pos = cnt - 1;
            bf16x8 a[8];
            if (lvl == 0) {
                int gl0 = b * NPT_ + child + 2 * pos;
                const ushort_t* pl = h + (size_t)gl0 * H_;
                const ushort_t* pr = h + (size_t)(gl0 + 1) * H_;
                #pragma unroll
                for (int kt = 0; kt < 8; ++kt) {
                    const ushort_t* p = (kt < 4) ? pl : pr;
                    a[kt] = *(const bf16x8*)(p + (kt & 3) * 32 + q8);
                }
            } else {
                int tl = (child - TBASE) + 2 * pos;
                #pragma unroll
                for (int kt = 0; kt < 8; ++kt) {
                    const ushort_t* p = (kt < 4) ? hl[tl] : hl[tl + 1];
                    a[kt] = *(const bf16x8*)(p + (kt & 3) * 32 + q8);
                }
            }

            float clv[4], crv[4];
            #pragma unroll
            for (int r = 0; r < 4; ++r) {
                int m  = i0 + q * 4 + r;
                int pm = m < cnt ? m : cnt - 1;
                if (lvl == 0) {
                    int gl = b * NPT_ + child + 2 * pm;
                    clv[r] = c[(size_t)gl * H_ + j];
                    crv[r] = c[(size_t)(gl + 1) * H_ + j];
                } else {
                    int tl = (child - TBASE) + 2 * pm;
                    clv[r] = cl[tl][j];
                    crv[r] = cl[tl + 1][j];
                }
            }

            f32x4 acc[5];
            #pragma unroll
            for (int t = 0; t < 5; ++t) acc[t] = (f32x4){0.f, 0.f, 0.f, 0.f};
            #pragma unroll
            for (int kt = 0; kt < 8; ++kt)
                #pragma unroll
                for (int t = 0; t < 5; ++t)
                    acc[t] = __builtin_amdgcn_mfma_f32_16x16x32_bf16(a[kt], Bf[t][kt], acc[t], 0, 0, 0);

            #pragma unroll
            for (int r = 0; r < 4; ++r) {
                int m = i0 + q * 4 + r;
                if (m < cnt) {
                    int tl = (base - TBASE) + m;
                    float iv = sigmoidf_(acc[0][r] + bi);
                    float ov = sigmoidf_(acc[1][r] + bo);
                    float uv = tanhf_(acc[2][r] + bu);
                    float fl = sigmoidf_(acc[3][r] + bfl);
                    float fr = sigmoidf_(acc[4][r] + bfr);
                    float cv = iv * uv + fl * clv[r] + fr * crv[r];
                    float hv = ov * tanhf_(cv);
                    cl[tl][j] = cv;
                    hl[tl][j] = f2bf(hv);
                }
            }
        }
        __syncthreads();
        child = base; base += cnt; cnt >>= 1;
    }

    if (tid < 128) ev[tid] = bf2f(hl[62][tid]);
    __syncthreads();

    // ---- output head: out[o] = b_out[o] + sum_k ev[k]*W_out[k][o] ----
    {
        const int o  = tid & 127;
        const int kc = tid >> 7;            // 0..3 -> k in [kc*32, kc*32+32)
        float pacc = (kc == 0) ? b_out[o] : 0.0f;
        #pragma unroll 8
        for (int k = kc * 32; k < kc * 32 + 32; ++k)
            pacc += ev[k] * W_out[k * OUT_ + o];
        red4[kc][o] = pacc;
    }
    __syncthreads();

    float acc = 0.0f;
    if (tid < 128) {
        acc = red4[0][tid] + red4[1][tid] + red4[2][tid] + red4[3][tid];
        red[tid] = acc;
    }
    __syncthreads();
    for (int s = 64; s > 0; s >>= 1) {
        if (tid < s) red[tid] = fmaxf(red[tid], red[tid + s]);
        __syncthreads();
    }
    float mx = red[0];
    __syncthreads();
    if (tid < 128) red[tid] = expf(acc - mx);
    __syncthreads();
    for (int s = 64; s > 0; s >>= 1) {
        if (tid < s) red[tid] += red[tid + s];
        __syncthreads();
    }
    float lse = logf(red[0]);
    if (tid < 128) out[b * OUT_ + tid] = acc - mx - lse;
}

// =====================================================================
extern "C" void kernel_launch(void* const* d_in, const int* in_sizes, int n_in,
                              void* d_out, int out_size, void* d_ws, size_t ws_size,
                              hipStream_t stream) {
    const int*   label = (const int*)d_in[0];
    const float* emb   = (const float*)d_in[1];
    const float* W_iou = (const float*)d_in[2];
    const float* U_iou = (const float*)d_in[3];
    const float* b_iou = (const float*)d_in[4];
    const float* U_f_w = (const float*)d_in[5];
    const float* U_f_b = (const float*)d_in[6];
    const float* W_out = (const float*)d_in[7];
    const float* b_out = (const float*)d_in[8];
    float* outp = (float*)d_out;

    // ws layout: c f32 | h bf16 | Ucat | WT | embb
    float*    c    = (float*)d_ws;
    ushort_t* h    = (ushort_t*)(c + (size_t)N_ * H_);
    ushort_t* Ucat = h + (size_t)N_ * H_;
    ushort_t* WT   = Ucat + 640 * 256;
    ushort_t* embb = WT + 384 * 128;

    prep_fused<<<2000, 256, 0, stream>>>(W_iou, U_iou, U_f_w, emb, WT, Ucat, embb);

    // leaf: 4096 M-tiles of 16; 512 stripes x 2 group-halves; 8 tiles/wave
    leaf_v3<<<dim3(512, 2), 256, 0, stream>>>(label, embb, WT, b_iou, h, c);

    // big levels: cnt = 256,128,64 — B in LDS, 2 tiles/wave (r15: more TLP)
    int child = 0, node = 512, cnt = 256, lc = 8;
    for (int lvl = 0; lvl < 3; ++lvl) {
        int ntiles  = (B_ * cnt) / 16;
        int stripes = ntiles / 8;           // 4 waves x 2 tiles per block
        level_lds<<<dim3(stripes, 8), 256, 0, stream>>>(
            Ucat, b_iou, U_f_b, h, c, node, child, lc, ntiles);
        child = node; node += cnt; cnt >>= 1; --lc;
    }

    // tail: cnt=32..1 + root, one block per tree
    tail_kernel<<<B_, 512, 0, stream>>>(Ucat, b_iou, U_f_b, h, c, W_out, b_out, outp);
}

// Round 6
// 232.349 us; speedup vs baseline: 1.9570x; 1.2000x over previous
//
#include <hip/hip_runtime.h>
#include <math.h>

// ---- Problem constants ----
#define B_    128
#define L_    512
#define H_    128
#define NPT_  1023
#define N_    (B_ * NPT_)     // 130944
#define NLEAF (B_ * L_)       // 65536
#define OUT_  128
#define VOCAB 32000
#define TBASE 960             // first tail node (cnt=32 level base)

typedef unsigned short ushort_t;
typedef __attribute__((ext_vector_type(8))) __bf16 bf16x8;
typedef __attribute__((ext_vector_type(4))) float f32x4;

__device__ __forceinline__ float sigmoidf_(float x) {
    return 1.0f / (1.0f + __expf(-x));
}
__device__ __forceinline__ float tanhf_(float x) {
    return 1.0f - 2.0f / (__expf(2.0f * x) + 1.0f);
}
__device__ __forceinline__ ushort_t f2bf(float f) {
    unsigned u = __float_as_uint(f);
    return (ushort_t)((u + 0x7fffu + ((u >> 16) & 1u)) >> 16);
}
__device__ __forceinline__ float bf2f(ushort_t s) {
    return __uint_as_float(((unsigned)s) << 16);
}

// =====================================================================
// Prep (fused): weights -> bf16 transposed, emb -> bf16.
// =====================================================================
__global__ __launch_bounds__(256)
void prep_fused(const float* __restrict__ W_iou,
                const float* __restrict__ U_iou,
                const float* __restrict__ U_f_w,
                const float* __restrict__ emb,
                ushort_t* __restrict__ W_iouT,     // [384][128]
                ushort_t* __restrict__ U_catT,     // [640][256]
                ushort_t* __restrict__ embb) {     // [VOCAB][128]
    int idx = blockIdx.x * 256 + threadIdx.x;
    if (idx < VOCAB * H_ / 8) {
        int e0 = idx * 8;
        f32x4 f0 = *(const f32x4*)(emb + e0);
        f32x4 f1 = *(const f32x4*)(emb + e0 + 4);
        union { bf16x8 v; ushort_t e[8]; } p;
        p.e[0] = f2bf(f0[0]); p.e[1] = f2bf(f0[1]);
        p.e[2] = f2bf(f0[2]); p.e[3] = f2bf(f0[3]);
        p.e[4] = f2bf(f1[0]); p.e[5] = f2bf(f1[1]);
        p.e[6] = f2bf(f1[2]); p.e[7] = f2bf(f1[3]);
        *(bf16x8*)(embb + e0) = p.v;
    }
    if (idx < 640 * 256) {
        int n = idx >> 8, k = idx & 255;
        float v = (n < 384) ? U_iou[k * 384 + n] : U_f_w[k * 256 + (n - 384)];
        U_catT[idx] = f2bf(v);
    }
    if (idx < 384 * 128) {
        int n = idx >> 7, k = idx & 127;
        W_iouT[idx] = f2bf(W_iou[k * 384 + n]);
    }
}

// =====================================================================
// Leaf (B register-resident, labels preloaded) — r13-verified; c f32.
// =====================================================================
__global__ __launch_bounds__(256, 4)
void leaf_v3(const int* __restrict__ label,
             const ushort_t* __restrict__ embb,
             const ushort_t* __restrict__ WT,
             const float* __restrict__ b_iou,
             ushort_t* __restrict__ h,
             float* __restrict__ c) {
    const int tid  = threadIdx.x;
    const int lane = tid & 63;
    const int wave = tid >> 6;
    const int li   = lane & 15;
    const int q    = lane >> 4;
    const int q8   = q << 3;
    const int gg   = blockIdx.y * 4 + wave;
    const int j    = gg * 16 + li;

    bf16x8 Bf[3][4];
    #pragma unroll
    for (int t = 0; t < 3; ++t) {
        const ushort_t* bp = WT + (size_t)(16 * (gg + 8 * t) + li) * 128 + q8;
        #pragma unroll
        for (int kt = 0; kt < 4; ++kt) Bf[t][kt] = *(const bf16x8*)(bp + kt * 32);
    }

    int lab[8];
    #pragma unroll
    for (int t = 0; t < 8; ++t) {
        int ia = (blockIdx.x + t * 512) * 16 + li;
        int ba = ia >> 9, pa = ia & 511;
        lab[t] = label[ba * NPT_ + pa];
    }

    const float bi = b_iou[j], bo = b_iou[128 + j], bu = b_iou[256 + j];

    #pragma unroll 1
    for (int t8 = 0; t8 < 8; ++t8) {
        const int tile = blockIdx.x + t8 * 512;
        const int i0 = tile * 16;
        const ushort_t* pA = embb + (size_t)lab[t8] * H_;
        bf16x8 a[4];
        #pragma unroll
        for (int kt = 0; kt < 4; ++kt) a[kt] = *(const bf16x8*)(pA + kt * 32 + q8);

        f32x4 acc[3];
        #pragma unroll
        for (int t = 0; t < 3; ++t) acc[t] = (f32x4){0.f, 0.f, 0.f, 0.f};
        #pragma unroll
        for (int kt = 0; kt < 4; ++kt)
            #pragma unroll
            for (int t = 0; t < 3; ++t)
                acc[t] = __builtin_amdgcn_mfma_f32_16x16x32_bf16(a[kt], Bf[t][kt], acc[t], 0, 0, 0);

        #pragma unroll
        for (int r = 0; r < 4; ++r) {
            int m  = i0 + q * 4 + r;
            int b  = m >> 9, pos = m & 511;
            size_t gn = (size_t)(b * NPT_ + pos) * H_ + j;
            float iv = sigmoidf_(acc[0][r] + bi);
            float ov = sigmoidf_(acc[1][r] + bo);
            float uv = tanhf_(acc[2][r] + bu);
            float cv = iv * uv;
            float hv = ov * tanhf_(cv);
            c[gn] = cv;
            h[gn] = f2bf(hv);
        }
    }
}

// =====================================================================
// Level, tail-style (r17): ONE 512-thread block = 8 waves = all 8 gate
// groups of the SAME M-tile. B in registers per wave (Bf[5][8], the
// tail kernel's verified pattern); NO LDS, NO barriers.
//  - A-fragments: 8 waves read the same 16 h_cat rows through the CU's
//    L1 -> children h read ONCE from L2/HBM (was 8x across gg-blocks).
//  - Outputs: the 8 waves' 32B(h)/64B(c) row chunks land in L2
//    concurrently -> full-line merge (was partial-line write-allocate).
// Tile body index math identical to r13-verified level_lds.
// =====================================================================
__global__ __launch_bounds__(512, 2)
void level_regB(const ushort_t* __restrict__ Ucat,
                const float* __restrict__ b_iou,
                const float* __restrict__ U_f_b,
                ushort_t* __restrict__ h,
                float* __restrict__ c,
                int node_base, int child_base, int lc, int ntiles) {
    const int tid  = threadIdx.x;
    const int lane = tid & 63;
    const int wave = tid >> 6;                      // = gate group 0..7
    const int li   = lane & 15;
    const int q    = lane >> 4;
    const int q8   = q << 3;
    const int mask = (1 << lc) - 1;
    const int gg   = wave;
    const int j    = gg * 16 + li;

    // ---- B slice in registers (tail pattern): 40 VGPR ----
    bf16x8 Bf[5][8];
    #pragma unroll
    for (int t = 0; t < 5; ++t) {
        const ushort_t* bp = Ucat + (size_t)(16 * (gg + 8 * t) + li) * 256 + q8;
        #pragma unroll
        for (int kt = 0; kt < 8; ++kt) Bf[t][kt] = *(const bf16x8*)(bp + kt * 32);
    }

    const float bi  = b_iou[j], bo = b_iou[128 + j], bu = b_iou[256 + j];
    const float bfl = U_f_b[j], bfr = U_f_b[128 + j];

    #pragma unroll 1
    for (int tile = blockIdx.x; tile < ntiles; tile += gridDim.x) {
        const int i0 = tile * 16;

        // epilogue c-children prefetch (independent; hides under K-loop)
        float clv[4], crv[4];
        int   gnrow[4];
        #pragma unroll
        for (int r = 0; r < 4; ++r) {
            int m = i0 + q * 4 + r;
            int b = m >> lc, pos = m & mask;
            int gl = b * NPT_ + child_base + 2 * pos;
            gnrow[r] = b * NPT_ + node_base + pos;
            clv[r] = c[(size_t)gl * H_ + j];
            crv[r] = c[(size_t)(gl + 1) * H_ + j];
        }

        // A: 16 h_cat rows; kt<4 left child, kt>=4 right child
        int ia = i0 + li, ba = ia >> lc, pa = ia & mask;
        int gl0 = ba * NPT_ + child_base + 2 * pa;
        const ushort_t* pl = h + (size_t)gl0 * H_;
        const ushort_t* pr = h + (size_t)(gl0 + 1) * H_;
        bf16x8 a[8];
        #pragma unroll
        for (int kt = 0; kt < 8; ++kt) {
            const ushort_t* p = (kt < 4) ? pl : pr;
            a[kt] = *(const bf16x8*)(p + (kt & 3) * 32 + q8);
        }

        f32x4 acc[5];
        #pragma unroll
        for (int t = 0; t < 5; ++t) acc[t] = (f32x4){0.f, 0.f, 0.f, 0.f};
        #pragma unroll
        for (int kt = 0; kt < 8; ++kt)
            #pragma unroll
            for (int t = 0; t < 5; ++t)
                acc[t] = __builtin_amdgcn_mfma_f32_16x16x32_bf16(a[kt], Bf[t][kt], acc[t], 0, 0, 0);

        #pragma unroll
        for (int r = 0; r < 4; ++r) {
            size_t gn = (size_t)gnrow[r] * H_ + j;
            float iv = sigmoidf_(acc[0][r] + bi);
            float ov = sigmoidf_(acc[1][r] + bo);
            float uv = tanhf_(acc[2][r] + bu);
            float fl = sigmoidf_(acc[3][r] + bfl);
            float fr = sigmoidf_(acc[4][r] + bfr);
            float cv = iv * uv + fl * clv[r] + fr * crv[r];
            float hv = ov * tanhf_(cv);
            c[gn] = cv;
            h[gn] = f2bf(hv);
        }
    }
}

// =====================================================================
// Tail — r13-verified: one block (8 waves = 8 gate groups) per TREE.
// Levels cnt=32..1 + root; tail h/c in LDS (63 nodes); c f32.
// Output head: 4-way K-parallel dot product across all 512 threads.
// =====================================================================
#define TPAD 132
__global__ __launch_bounds__(512, 2)
void tail_kernel(const ushort_t* __restrict__ Ucat,
                 const float* __restrict__ b_iou,
                 const float* __restrict__ U_f_b,
                 const ushort_t* __restrict__ h,
                 const float* __restrict__ c,
                 const float* __restrict__ W_out,
                 const float* __restrict__ b_out,
                 float* __restrict__ out) {
    __shared__ ushort_t hl[63][TPAD];
    __shared__ float    cl[63][TPAD];
    __shared__ float    ev[H_];
    __shared__ float    red[128];
    __shared__ float    red4[4][128];

    const int tid  = threadIdx.x;
    const int lane = tid & 63;
    const int wave = tid >> 6;
    const int li   = lane & 15;
    const int q    = lane >> 4;
    const int q8   = q << 3;
    const int gg   = wave;
    const int j    = gg * 16 + li;
    const int b    = blockIdx.x;

    bf16x8 Bf[5][8];
    #pragma unroll
    for (int t = 0; t < 5; ++t) {
        const ushort_t* bp = Ucat + (size_t)(16 * (gg + 8 * t) + li) * 256 + q8;
        #pragma unroll
        for (int kt = 0; kt < 8; ++kt) Bf[t][kt] = *(const bf16x8*)(bp + kt * 32);
    }

    const float bi  = b_iou[j], bo = b_iou[128 + j], bu = b_iou[256 + j];
    const float bfl = U_f_b[j], bfr = U_f_b[128 + j];

    int base = TBASE, child = 896, cnt = 32;
    #pragma unroll 1
    for (int lvl = 0; lvl < 6; ++lvl) {
        const int tiles = (cnt + 15) >> 4;
        for (int tile = 0; tile < tiles; ++tile) {
            const int i0 = tile * 16;

            int pos = i0 + li; if (pos >= cnt) pos = cnt - 1;
            bf16x8 a[8];
            if (lvl == 0) {
                int gl0 = b * NPT_ + child + 2 * pos;
                const ushort_t* pl = h + (size_t)gl0 * H_;
                const ushort_t* pr = h + (size_t)(gl0 + 1) * H_;
                #pragma unroll
                for (int kt = 0; kt < 8; ++kt) {
                    const ushort_t* p = (kt < 4) ? pl : pr;
                    a[kt] = *(const bf16x8*)(p + (kt & 3) * 32 + q8);
                }
            } else {
                int tl = (child - TBASE) + 2 * pos;
                #pragma unroll
                for (int kt = 0; kt < 8; ++kt) {
                    const ushort_t* p = (kt < 4) ? hl[tl] : hl[tl + 1];
                    a[kt] = *(const bf16x8*)(p + (kt & 3) * 32 + q8);
                }
            }

            float clv[4], crv[4];
            #pragma unroll
            for (int r = 0; r < 4; ++r) {
                int m  = i0 + q * 4 + r;
                int pm = m < cnt ? m : cnt - 1;
                if (lvl == 0) {
                    int gl = b * NPT_ + child + 2 * pm;
                    clv[r] = c[(size_t)gl * H_ + j];
                    crv[r] = c[(size_t)(gl + 1) * H_ + j];
                } else {
                    int tl = (child - TBASE) + 2 * pm;
                    clv[r] = cl[tl][j];
                    crv[r] = cl[tl + 1][j];
                }
            }

            f32x4 acc[5];
            #pragma unroll
            for (int t = 0; t < 5; ++t) acc[t] = (f32x4){0.f, 0.f, 0.f, 0.f};
            #pragma unroll
            for (int kt = 0; kt < 8; ++kt)
                #pragma unroll
                for (int t = 0; t < 5; ++t)
                    acc[t] = __builtin_amdgcn_mfma_f32_16x16x32_bf16(a[kt], Bf[t][kt], acc[t], 0, 0, 0);

            #pragma unroll
            for (int r = 0; r < 4; ++r) {
                int m = i0 + q * 4 + r;
                if (m < cnt) {
                    int tl = (base - TBASE) + m;
                    float iv = sigmoidf_(acc[0][r] + bi);
                    float ov = sigmoidf_(acc[1][r] + bo);
                    float uv = tanhf_(acc[2][r] + bu);
                    float fl = sigmoidf_(acc[3][r] + bfl);
                    float fr = sigmoidf_(acc[4][r] + bfr);
                    float cv = iv * uv + fl * clv[r] + fr * crv[r];
                    float hv = ov * tanhf_(cv);
                    cl[tl][j] = cv;
                    hl[tl][j] = f2bf(hv);
                }
            }
        }
        __syncthreads();
        child = base; base += cnt; cnt >>= 1;
    }

    if (tid < 128) ev[tid] = bf2f(hl[62][tid]);
    __syncthreads();

    // ---- output head: out[o] = b_out[o] + sum_k ev[k]*W_out[k][o] ----
    {
        const int o  = tid & 127;
        const int kc = tid >> 7;            // 0..3 -> k in [kc*32, kc*32+32)
        float pacc = (kc == 0) ? b_out[o] : 0.0f;
        #pragma unroll 8
        for (int k = kc * 32; k < kc * 32 + 32; ++k)
            pacc += ev[k] * W_out[k * OUT_ + o];
        red4[kc][o] = pacc;
    }
    __syncthreads();

    float acc = 0.0f;
    if (tid < 128) {
        acc = red4[0][tid] + red4[1][tid] + red4[2][tid] + red4[3][tid];
        red[tid] = acc;
    }
    __syncthreads();
    for (int s = 64; s > 0; s >>= 1) {
        if (tid < s) red[tid] = fmaxf(red[tid], red[tid + s]);
        __syncthreads();
    }
    float mx = red[0];
    __syncthreads();
    if (tid < 128) red[tid] = expf(acc - mx);
    __syncthreads();
    for (int s = 64; s > 0; s >>= 1) {
        if (tid < s) red[tid] += red[tid + s];
        __syncthreads();
    }
    float lse = logf(red[0]);
    if (tid < 128) out[b * OUT_ + tid] = acc - mx - lse;
}

// =====================================================================
extern "C" void kernel_launch(void* const* d_in, const int* in_sizes, int n_in,
                              void* d_out, int out_size, void* d_ws, size_t ws_size,
                              hipStream_t stream) {
    const int*   label = (const int*)d_in[0];
    const float* emb   = (const float*)d_in[1];
    const float* W_iou = (const float*)d_in[2];
    const float* U_iou = (const float*)d_in[3];
    const float* b_iou = (const float*)d_in[4];
    const float* U_f_w = (const float*)d_in[5];
    const float* U_f_b = (const float*)d_in[6];
    const float* W_out = (const float*)d_in[7];
    const float* b_out = (const float*)d_in[8];
    float* outp = (float*)d_out;

    // ws layout: c f32 | h bf16 | Ucat | WT | embb
    float*    c    = (float*)d_ws;
    ushort_t* h    = (ushort_t*)(c + (size_t)N_ * H_);
    ushort_t* Ucat = h + (size_t)N_ * H_;
    ushort_t* WT   = Ucat + 640 * 256;
    ushort_t* embb = WT + 384 * 128;

    prep_fused<<<2000, 256, 0, stream>>>(W_iou, U_iou, U_f_w, emb, WT, Ucat, embb);

    // leaf: 4096 M-tiles of 16; 512 stripes x 2 group-halves; 8 tiles/wave
    leaf_v3<<<dim3(512, 2), 256, 0, stream>>>(label, embb, WT, b_iou, h, c);

    // big levels: cnt = 256,128,64 — tail-style blocks (8 waves = 8 gg
    // on the same tile), 4 tiles/block grid-stride.
    int child = 0, node = 512, cnt = 256, lc = 8;
    for (int lvl = 0; lvl < 3; ++lvl) {
        int ntiles = (B_ * cnt) / 16;
        int nblk   = ntiles / 4;            // L0: 512, L1: 256, L2: 128
        level_regB<<<nblk, 512, 0, stream>>>(
            Ucat, b_iou, U_f_b, h, c, node, child, lc, ntiles);
        child = node; node += cnt; cnt >>= 1; --lc;
    }

    // tail: cnt=32..1 + root, one block per tree
    tail_kernel<<<B_, 512, 0, stream>>>(Ucat, b_iou, U_f_b, h, c, W_out, b_out, outp);
}

// Round 7
// 217.729 us; speedup vs baseline: 2.0884x; 1.0671x over previous
//
#include <hip/hip_runtime.h>
#include <math.h>

// ---- Problem constants ----
#define B_    128
#define L_    512
#define H_    128
#define NPT_  1023
#define N_    (B_ * NPT_)     // 130944
#define NLEAF (B_ * L_)       // 65536
#define OUT_  128
#define VOCAB 32000
#define TBASE 960             // first tail node (cnt=32 level base)

typedef unsigned short ushort_t;
typedef __attribute__((ext_vector_type(8))) __bf16 bf16x8;
typedef __attribute__((ext_vector_type(4))) float f32x4;

__device__ __forceinline__ float sigmoidf_(float x) {
    return 1.0f / (1.0f + __expf(-x));
}
__device__ __forceinline__ float tanhf_(float x) {
    return 1.0f - 2.0f / (__expf(2.0f * x) + 1.0f);
}
__device__ __forceinline__ ushort_t f2bf(float f) {
    unsigned u = __float_as_uint(f);
    return (ushort_t)((u + 0x7fffu + ((u >> 16) & 1u)) >> 16);
}
__device__ __forceinline__ float bf2f(ushort_t s) {
    return __uint_as_float(((unsigned)s) << 16);
}

// =====================================================================
// Prep (fused): weights -> bf16 transposed, emb -> bf16.
// =====================================================================
__global__ __launch_bounds__(256)
void prep_fused(const float* __restrict__ W_iou,
                const float* __restrict__ U_iou,
                const float* __restrict__ U_f_w,
                const float* __restrict__ emb,
                ushort_t* __restrict__ W_iouT,     // [384][128]
                ushort_t* __restrict__ U_catT,     // [640][256]
                ushort_t* __restrict__ embb) {     // [VOCAB][128]
    int idx = blockIdx.x * 256 + threadIdx.x;
    if (idx < VOCAB * H_ / 8) {
        int e0 = idx * 8;
        f32x4 f0 = *(const f32x4*)(emb + e0);
        f32x4 f1 = *(const f32x4*)(emb + e0 + 4);
        union { bf16x8 v; ushort_t e[8]; } p;
        p.e[0] = f2bf(f0[0]); p.e[1] = f2bf(f0[1]);
        p.e[2] = f2bf(f0[2]); p.e[3] = f2bf(f0[3]);
        p.e[4] = f2bf(f1[0]); p.e[5] = f2bf(f1[1]);
        p.e[6] = f2bf(f1[2]); p.e[7] = f2bf(f1[3]);
        *(bf16x8*)(embb + e0) = p.v;
    }
    if (idx < 640 * 256) {
        int n = idx >> 8, k = idx & 255;
        float v = (n < 384) ? U_iou[k * 384 + n] : U_f_w[k * 256 + (n - 384)];
        U_catT[idx] = f2bf(v);
    }
    if (idx < 384 * 128) {
        int n = idx >> 7, k = idx & 127;
        W_iouT[idx] = f2bf(W_iou[k * 384 + n]);
    }
}

// =====================================================================
// Leaf (B register-resident, labels preloaded) — r13-verified; c f32.
// =====================================================================
__global__ __launch_bounds__(256, 4)
void leaf_v3(const int* __restrict__ label,
             const ushort_t* __restrict__ embb,
             const ushort_t* __restrict__ WT,
             const float* __restrict__ b_iou,
             ushort_t* __restrict__ h,
             float* __restrict__ c) {
    const int tid  = threadIdx.x;
    const int lane = tid & 63;
    const int wave = tid >> 6;
    const int li   = lane & 15;
    const int q    = lane >> 4;
    const int q8   = q << 3;
    const int gg   = blockIdx.y * 4 + wave;
    const int j    = gg * 16 + li;

    bf16x8 Bf[3][4];
    #pragma unroll
    for (int t = 0; t < 3; ++t) {
        const ushort_t* bp = WT + (size_t)(16 * (gg + 8 * t) + li) * 128 + q8;
        #pragma unroll
        for (int kt = 0; kt < 4; ++kt) Bf[t][kt] = *(const bf16x8*)(bp + kt * 32);
    }

    int lab[8];
    #pragma unroll
    for (int t = 0; t < 8; ++t) {
        int ia = (blockIdx.x + t * 512) * 16 + li;
        int ba = ia >> 9, pa = ia & 511;
        lab[t] = label[ba * NPT_ + pa];
    }

    const float bi = b_iou[j], bo = b_iou[128 + j], bu = b_iou[256 + j];

    #pragma unroll 1
    for (int t8 = 0; t8 < 8; ++t8) {
        const int tile = blockIdx.x + t8 * 512;
        const int i0 = tile * 16;
        const ushort_t* pA = embb + (size_t)lab[t8] * H_;
        bf16x8 a[4];
        #pragma unroll
        for (int kt = 0; kt < 4; ++kt) a[kt] = *(const bf16x8*)(pA + kt * 32 + q8);

        f32x4 acc[3];
        #pragma unroll
        for (int t = 0; t < 3; ++t) acc[t] = (f32x4){0.f, 0.f, 0.f, 0.f};
        #pragma unroll
        for (int kt = 0; kt < 4; ++kt)
            #pragma unroll
            for (int t = 0; t < 3; ++t)
                acc[t] = __builtin_amdgcn_mfma_f32_16x16x32_bf16(a[kt], Bf[t][kt], acc[t], 0, 0, 0);

        #pragma unroll
        for (int r = 0; r < 4; ++r) {
            int m  = i0 + q * 4 + r;
            int b  = m >> 9, pos = m & 511;
            size_t gn = (size_t)(b * NPT_ + pos) * H_ + j;
            float iv = sigmoidf_(acc[0][r] + bi);
            float ov = sigmoidf_(acc[1][r] + bo);
            float uv = tanhf_(acc[2][r] + bu);
            float cv = iv * uv;
            float hv = ov * tanhf_(cv);
            c[gn] = cv;
            h[gn] = f2bf(hv);
        }
    }
}

// =====================================================================
// Level, tail-style (r17/r18): ONE 512-thread block = 8 waves = all 8
// gate groups of the SAME M-tile. NO LDS, NO barriers.
// r18: VGPR_Count=120 proved the compiler SANK the 40 B-fragment loads
// into the tile loop (re-read 327KB/block/tile from L2 -> latency chain,
// MfmaUtil 8%). Fix: keep-alive asm on each fragment pins B in VGPRs
// (~240 total -> 2 waves/SIMD, 1 block/CU); grid = 256 blocks (1/CU),
// tiles amortize the B prologue.
// =====================================================================
__global__ __launch_bounds__(512, 2)
void level_regB(const ushort_t* __restrict__ Ucat,
                const float* __restrict__ b_iou,
                const float* __restrict__ U_f_b,
                ushort_t* __restrict__ h,
                float* __restrict__ c,
                int node_base, int child_base, int lc, int ntiles) {
    const int tid  = threadIdx.x;
    const int lane = tid & 63;
    const int wave = tid >> 6;                      // = gate group 0..7
    const int li   = lane & 15;
    const int q    = lane >> 4;
    const int q8   = q << 3;
    const int mask = (1 << lc) - 1;
    const int gg   = wave;
    const int j    = gg * 16 + li;

    // ---- B slice pinned in registers: 40 x f32x4 = 160 VGPR ----
    f32x4 Bf[5][8];
    #pragma unroll
    for (int t = 0; t < 5; ++t) {
        const ushort_t* bp = Ucat + (size_t)(16 * (gg + 8 * t) + li) * 256 + q8;
        #pragma unroll
        for (int kt = 0; kt < 8; ++kt) Bf[t][kt] = *(const f32x4*)(bp + kt * 32);
    }
    // keep-alive: "modifies" each fragment -> compiler cannot re-load
    // from Ucat inside the loop; B stays VGPR-resident.
    #pragma unroll
    for (int t = 0; t < 5; ++t)
        #pragma unroll
        for (int kt = 0; kt < 8; ++kt)
            asm volatile("" : "+v"(Bf[t][kt]));

    const float bi  = b_iou[j], bo = b_iou[128 + j], bu = b_iou[256 + j];
    const float bfl = U_f_b[j], bfr = U_f_b[128 + j];

    #pragma unroll 1
    for (int tile = blockIdx.x; tile < ntiles; tile += gridDim.x) {
        const int i0 = tile * 16;

        // epilogue c-children prefetch (independent; hides under K-loop)
        float clv[4], crv[4];
        int   gnrow[4];
        #pragma unroll
        for (int r = 0; r < 4; ++r) {
            int m = i0 + q * 4 + r;
            int b = m >> lc, pos = m & mask;
            int gl = b * NPT_ + child_base + 2 * pos;
            gnrow[r] = b * NPT_ + node_base + pos;
            clv[r] = c[(size_t)gl * H_ + j];
            crv[r] = c[(size_t)(gl + 1) * H_ + j];
        }

        // A: 16 h_cat rows; kt<4 left child, kt>=4 right child
        int ia = i0 + li, ba = ia >> lc, pa = ia & mask;
        int gl0 = ba * NPT_ + child_base + 2 * pa;
        const ushort_t* pl = h + (size_t)gl0 * H_;
        const ushort_t* pr = h + (size_t)(gl0 + 1) * H_;
        bf16x8 a[8];
        #pragma unroll
        for (int kt = 0; kt < 8; ++kt) {
            const ushort_t* p = (kt < 4) ? pl : pr;
            a[kt] = *(const bf16x8*)(p + (kt & 3) * 32 + q8);
        }

        f32x4 acc[5];
        #pragma unroll
        for (int t = 0; t < 5; ++t) acc[t] = (f32x4){0.f, 0.f, 0.f, 0.f};
        #pragma unroll
        for (int kt = 0; kt < 8; ++kt)
            #pragma unroll
            for (int t = 0; t < 5; ++t)
                acc[t] = __builtin_amdgcn_mfma_f32_16x16x32_bf16(
                    a[kt], __builtin_bit_cast(bf16x8, Bf[t][kt]), acc[t], 0, 0, 0);

        #pragma unroll
        for (int r = 0; r < 4; ++r) {
            size_t gn = (size_t)gnrow[r] * H_ + j;
            float iv = sigmoidf_(acc[0][r] + bi);
            float ov = sigmoidf_(acc[1][r] + bo);
            float uv = tanhf_(acc[2][r] + bu);
            float fl = sigmoidf_(acc[3][r] + bfl);
            float fr = sigmoidf_(acc[4][r] + bfr);
            float cv = iv * uv + fl * clv[r] + fr * crv[r];
            float hv = ov * tanhf_(cv);
            c[gn] = cv;
            h[gn] = f2bf(hv);
        }
    }
}

// =====================================================================
// Tail — r13-verified: one block (8 waves = 8 gate groups) per TREE.
// Levels cnt=32..1 + root; tail h/c in LDS (63 nodes); c f32.
// Output head: 4-way K-parallel dot product across all 512 threads.
// =====================================================================
#define TPAD 132
__global__ __launch_bounds__(512, 2)
void tail_kernel(const ushort_t* __restrict__ Ucat,
                 const float* __restrict__ b_iou,
                 const float* __restrict__ U_f_b,
                 const ushort_t* __restrict__ h,
                 const float* __restrict__ c,
                 const float* __restrict__ W_out,
                 const float* __restrict__ b_out,
                 float* __restrict__ out) {
    __shared__ ushort_t hl[63][TPAD];
    __shared__ float    cl[63][TPAD];
    __shared__ float    ev[H_];
    __shared__ float    red[128];
    __shared__ float    red4[4][128];

    const int tid  = threadIdx.x;
    const int lane = tid & 63;
    const int wave = tid >> 6;
    const int li   = lane & 15;
    const int q    = lane >> 4;
    const int q8   = q << 3;
    const int gg   = wave;
    const int j    = gg * 16 + li;
    const int b    = blockIdx.x;

    bf16x8 Bf[5][8];
    #pragma unroll
    for (int t = 0; t < 5; ++t) {
        const ushort_t* bp = Ucat + (size_t)(16 * (gg + 8 * t) + li) * 256 + q8;
        #pragma unroll
        for (int kt = 0; kt < 8; ++kt) Bf[t][kt] = *(const bf16x8*)(bp + kt * 32);
    }

    const float bi  = b_iou[j], bo = b_iou[128 + j], bu = b_iou[256 + j];
    const float bfl = U_f_b[j], bfr = U_f_b[128 + j];

    int base = TBASE, child = 896, cnt = 32;
    #pragma unroll 1
    for (int lvl = 0; lvl < 6; ++lvl) {
        const int tiles = (cnt + 15) >> 4;
        for (int tile = 0; tile < tiles; ++tile) {
            const int i0 = tile * 16;

            int pos = i0 + li; if (pos >= cnt) pos = cnt - 1;
            bf16x8 a[8];
            if (lvl == 0) {
                int gl0 = b * NPT_ + child + 2 * pos;
                const ushort_t* pl = h + (size_t)gl0 * H_;
                const ushort_t* pr = h + (size_t)(gl0 + 1) * H_;
                #pragma unroll
                for (int kt = 0; kt < 8; ++kt) {
                    const ushort_t* p = (kt < 4) ? pl : pr;
                    a[kt] = *(const bf16x8*)(p + (kt & 3) * 32 + q8);
                }
            } else {
                int tl = (child - TBASE) + 2 * pos;
                #pragma unroll
                for (int kt = 0; kt < 8; ++kt) {
                    const ushort_t* p = (kt < 4) ? hl[tl] : hl[tl + 1];
                    a[kt] = *(const bf16x8*)(p + (kt & 3) * 32 + q8);
                }
            }

            float clv[4], crv[4];
            #pragma unroll
            for (int r = 0; r < 4; ++r) {
                int m  = i0 + q * 4 + r;
                int pm = m < cnt ? m : cnt - 1;
                if (lvl == 0) {
                    int gl = b * NPT_ + child + 2 * pm;
                    clv[r] = c[(size_t)gl * H_ + j];
                    crv[r] = c[(size_t)(gl + 1) * H_ + j];
                } else {
                    int tl = (child - TBASE) + 2 * pm;
                    clv[r] = cl[tl][j];
                    crv[r] = cl[tl + 1][j];
                }
            }

            f32x4 acc[5];
            #pragma unroll
            for (int t = 0; t < 5; ++t) acc[t] = (f32x4){0.f, 0.f, 0.f, 0.f};
            #pragma unroll
            for (int kt = 0; kt < 8; ++kt)
                #pragma unroll
                for (int t = 0; t < 5; ++t)
                    acc[t] = __builtin_amdgcn_mfma_f32_16x16x32_bf16(a[kt], Bf[t][kt], acc[t], 0, 0, 0);

            #pragma unroll
            for (int r = 0; r < 4; ++r) {
                int m = i0 + q * 4 + r;
                if (m < cnt) {
                    int tl = (base - TBASE) + m;
                    float iv = sigmoidf_(acc[0][r] + bi);
                    float ov = sigmoidf_(acc[1][r] + bo);
                    float uv = tanhf_(acc[2][r] + bu);
                    float fl = sigmoidf_(acc[3][r] + bfl);
                    float fr = sigmoidf_(acc[4][r] + bfr);
                    float cv = iv * uv + fl * clv[r] + fr * crv[r];
                    float hv = ov * tanhf_(cv);
                    cl[tl][j] = cv;
                    hl[tl][j] = f2bf(hv);
                }
            }
        }
        __syncthreads();
        child = base; base += cnt; cnt >>= 1;
    }

    if (tid < 128) ev[tid] = bf2f(hl[62][tid]);
    __syncthreads();

    // ---- output head: out[o] = b_out[o] + sum_k ev[k]*W_out[k][o] ----
    {
        const int o  = tid & 127;
        const int kc = tid >> 7;            // 0..3 -> k in [kc*32, kc*32+32)
        float pacc = (kc == 0) ? b_out[o] : 0.0f;
        #pragma unroll 8
        for (int k = kc * 32; k < kc * 32 + 32; ++k)
            pacc += ev[k] * W_out[k * OUT_ + o];
        red4[kc][o] = pacc;
    }
    __syncthreads();

    float acc = 0.0f;
    if (tid < 128) {
        acc = red4[0][tid] + red4[1][tid] + red4[2][tid] + red4[3][tid];
        red[tid] = acc;
    }
    __syncthreads();
    for (int s = 64; s > 0; s >>= 1) {
        if (tid < s) red[tid] = fmaxf(red[tid], red[tid + s]);
        __syncthreads();
    }
    float mx = red[0];
    __syncthreads();
    if (tid < 128) red[tid] = expf(acc - mx);
    __syncthreads();
    for (int s = 64; s > 0; s >>= 1) {
        if (tid < s) red[tid] += red[tid + s];
        __syncthreads();
    }
    float lse = logf(red[0]);
    if (tid < 128) out[b * OUT_ + tid] = acc - mx - lse;
}

// =====================================================================
extern "C" void kernel_launch(void* const* d_in, const int* in_sizes, int n_in,
                              void* d_out, int out_size, void* d_ws, size_t ws_size,
                              hipStream_t stream) {
    const int*   label = (const int*)d_in[0];
    const float* emb   = (const float*)d_in[1];
    const float* W_iou = (const float*)d_in[2];
    const float* U_iou = (const float*)d_in[3];
    const float* b_iou = (const float*)d_in[4];
    const float* U_f_w = (const float*)d_in[5];
    const float* U_f_b = (const float*)d_in[6];
    const float* W_out = (const float*)d_in[7];
    const float* b_out = (const float*)d_in[8];
    float* outp = (float*)d_out;

    // ws layout: c f32 | h bf16 | Ucat | WT | embb
    float*    c    = (float*)d_ws;
    ushort_t* h    = (ushort_t*)(c + (size_t)N_ * H_);
    ushort_t* Ucat = h + (size_t)N_ * H_;
    ushort_t* WT   = Ucat + 640 * 256;
    ushort_t* embb = WT + 384 * 128;

    prep_fused<<<2000, 256, 0, stream>>>(W_iou, U_iou, U_f_w, emb, WT, Ucat, embb);

    // leaf: 4096 M-tiles of 16; 512 stripes x 2 group-halves; 8 tiles/wave
    leaf_v3<<<dim3(512, 2), 256, 0, stream>>>(label, embb, WT, b_iou, h, c);

    // big levels: cnt = 256,128,64 — tail-style blocks (8 waves = 8 gg
    // on the same tile); 256 blocks = 1/CU, B pinned in VGPRs (r18).
    int child = 0, node = 512, cnt = 256, lc = 8;
    for (int lvl = 0; lvl < 3; ++lvl) {
        int ntiles = (B_ * cnt) / 16;
        level_regB<<<256, 512, 0, stream>>>(
            Ucat, b_iou, U_f_b, h, c, node, child, lc, ntiles);
        child = node; node += cnt; cnt >>= 1; --lc;
    }

    // tail: cnt=32..1 + root, one block per tree
    tail_kernel<<<B_, 512, 0, stream>>>(Ucat, b_iou, U_f_b, h, c, W_out, b_out, outp);
}

// Round 8
// 198.781 us; speedup vs baseline: 2.2874x; 1.0953x over previous
//
#include <hip/hip_runtime.h>
#include <math.h>

// ---- Problem constants ----
#define B_    128
#define L_    512
#define H_    128
#define NPT_  1023
#define N_    (B_ * NPT_)     // 130944
#define NLEAF (B_ * L_)       // 65536
#define OUT_  128
#define VOCAB 32000
#define TBASE 960             // first tail node (cnt=32 level base)
#define BROW  264             // padded LDS B-row (256+8 shorts): 2-way = free

typedef unsigned short ushort_t;
typedef __attribute__((ext_vector_type(8))) __bf16 bf16x8;
typedef __attribute__((ext_vector_type(4))) float f32x4;

__device__ __forceinline__ float sigmoidf_(float x) {
    return 1.0f / (1.0f + __expf(-x));
}
__device__ __forceinline__ float tanhf_(float x) {
    return 1.0f - 2.0f / (__expf(2.0f * x) + 1.0f);
}
__device__ __forceinline__ ushort_t f2bf(float f) {
    unsigned u = __float_as_uint(f);
    return (ushort_t)((u + 0x7fffu + ((u >> 16) & 1u)) >> 16);
}
__device__ __forceinline__ float bf2f(ushort_t s) {
    return __uint_as_float(((unsigned)s) << 16);
}

// =====================================================================
// Prep (fused): weights -> bf16 transposed, emb -> bf16.
// =====================================================================
__global__ __launch_bounds__(256)
void prep_fused(const float* __restrict__ W_iou,
                const float* __restrict__ U_iou,
                const float* __restrict__ U_f_w,
                const float* __restrict__ emb,
                ushort_t* __restrict__ W_iouT,     // [384][128]
                ushort_t* __restrict__ U_catT,     // [640][256]
                ushort_t* __restrict__ embb) {     // [VOCAB][128]
    int idx = blockIdx.x * 256 + threadIdx.x;
    if (idx < VOCAB * H_ / 8) {
        int e0 = idx * 8;
        f32x4 f0 = *(const f32x4*)(emb + e0);
        f32x4 f1 = *(const f32x4*)(emb + e0 + 4);
        union { bf16x8 v; ushort_t e[8]; } p;
        p.e[0] = f2bf(f0[0]); p.e[1] = f2bf(f0[1]);
        p.e[2] = f2bf(f0[2]); p.e[3] = f2bf(f0[3]);
        p.e[4] = f2bf(f1[0]); p.e[5] = f2bf(f1[1]);
        p.e[6] = f2bf(f1[2]); p.e[7] = f2bf(f1[3]);
        *(bf16x8*)(embb + e0) = p.v;
    }
    if (idx < 640 * 256) {
        int n = idx >> 8, k = idx & 255;
        float v = (n < 384) ? U_iou[k * 384 + n] : U_f_w[k * 256 + (n - 384)];
        U_catT[idx] = f2bf(v);
    }
    if (idx < 384 * 128) {
        int n = idx >> 7, k = idx & 127;
        W_iouT[idx] = f2bf(W_iou[k * 384 + n]);
    }
}

// =====================================================================
// Leaf (B register-resident, labels preloaded) — r13-verified; c f32.
// =====================================================================
__global__ __launch_bounds__(256, 4)
void leaf_v3(const int* __restrict__ label,
             const ushort_t* __restrict__ embb,
             const ushort_t* __restrict__ WT,
             const float* __restrict__ b_iou,
             ushort_t* __restrict__ h,
             float* __restrict__ c) {
    const int tid  = threadIdx.x;
    const int lane = tid & 63;
    const int wave = tid >> 6;
    const int li   = lane & 15;
    const int q    = lane >> 4;
    const int q8   = q << 3;
    const int gg   = blockIdx.y * 4 + wave;
    const int j    = gg * 16 + li;

    bf16x8 Bf[3][4];
    #pragma unroll
    for (int t = 0; t < 3; ++t) {
        const ushort_t* bp = WT + (size_t)(16 * (gg + 8 * t) + li) * 128 + q8;
        #pragma unroll
        for (int kt = 0; kt < 4; ++kt) Bf[t][kt] = *(const bf16x8*)(bp + kt * 32);
    }

    int lab[8];
    #pragma unroll
    for (int t = 0; t < 8; ++t) {
        int ia = (blockIdx.x + t * 512) * 16 + li;
        int ba = ia >> 9, pa = ia & 511;
        lab[t] = label[ba * NPT_ + pa];
    }

    const float bi = b_iou[j], bo = b_iou[128 + j], bu = b_iou[256 + j];

    #pragma unroll 1
    for (int t8 = 0; t8 < 8; ++t8) {
        const int tile = blockIdx.x + t8 * 512;
        const int i0 = tile * 16;
        const ushort_t* pA = embb + (size_t)lab[t8] * H_;
        bf16x8 a[4];
        #pragma unroll
        for (int kt = 0; kt < 4; ++kt) a[kt] = *(const bf16x8*)(pA + kt * 32 + q8);

        f32x4 acc[3];
        #pragma unroll
        for (int t = 0; t < 3; ++t) acc[t] = (f32x4){0.f, 0.f, 0.f, 0.f};
        #pragma unroll
        for (int kt = 0; kt < 4; ++kt)
            #pragma unroll
            for (int t = 0; t < 3; ++t)
                acc[t] = __builtin_amdgcn_mfma_f32_16x16x32_bf16(a[kt], Bf[t][kt], acc[t], 0, 0, 0);

        #pragma unroll
        for (int r = 0; r < 4; ++r) {
            int m  = i0 + q * 4 + r;
            int b  = m >> 9, pos = m & 511;
            size_t gn = (size_t)(b * NPT_ + pos) * H_ + j;
            float iv = sigmoidf_(acc[0][r] + bi);
            float ov = sigmoidf_(acc[1][r] + bo);
            float uv = tanhf_(acc[2][r] + bu);
            float cv = iv * uv;
            float hv = ov * tanhf_(cv);
            c[gn] = cv;
            h[gn] = f2bf(hv);
        }
    }
}

// =====================================================================
// Level, B in LDS, M=16/wave — r2-verified body (199 us total).
// r19: 1-D grid with XCD swizzle. x = 64*chunk + 8*gg + r maps the 8
// gate-group blocks of stripe s = 8*chunk + r ADJACENT in dispatch
// order (co-resident) and on the SAME XCD (x % 8 == r for all 8):
//  - A h-rows fetched from HBM once per stripe into that XCD's L2
//    (was 8x: gg-blocks ran at different times, L2 evicted between).
//  - The 8 disjoint 64B write-chunks of each output row merge into
//    full lines in that XCD's L2 (was partial-line write-allocate).
// Kernel body / launch bounds byte-identical to r2.
// =====================================================================
__global__ __launch_bounds__(256, 2)
void level_lds(const ushort_t* __restrict__ Ucat,
               const float* __restrict__ b_iou,
               const float* __restrict__ U_f_b,
               ushort_t* __restrict__ h,
               float* __restrict__ c,
               int node_base, int child_base, int lc, int ntiles) {
    __shared__ ushort_t Bs[5 * 16 * BROW];          // 42.2 KB
    const int tid  = threadIdx.x;
    const int lane = tid & 63;
    const int wave = tid >> 6;
    const int li   = lane & 15;
    const int q    = lane >> 4;
    const int q8   = q << 3;
    const int mask = (1 << lc) - 1;

    // ---- XCD swizzle: (gg, stripe) from 1-D blockIdx ----
    const int bx      = blockIdx.x;
    const int gg      = (bx >> 3) & 7;              // gate group 0..7
    const int s       = ((bx >> 6) << 3) | (bx & 7);// stripe
    const int stripes = gridDim.x >> 3;
    const int j       = gg * 16 + li;

    // ---- stage B: 80 rows x 256 shorts, coalesced 32B chunks ----
    #pragma unroll
    for (int it = 0; it < 5; ++it) {
        int chunk = tid + it * 256;                 // 0..1279
        int row = chunk >> 4, seg = chunk & 15;
        int t = row >> 4, lr = row & 15;
        const ushort_t* src = Ucat + (size_t)(16 * (gg + 8 * t) + lr) * 256 + seg * 16;
        ushort_t*       dst = Bs + (t * 16 + lr) * BROW + seg * 16;
        *(f32x4*)(dst)     = *(const f32x4*)(src);
        *(f32x4*)(dst + 8) = *(const f32x4*)(src + 8);
    }
    __syncthreads();

    const float bi  = b_iou[j], bo = b_iou[128 + j], bu = b_iou[256 + j];
    const float bfl = U_f_b[j], bfr = U_f_b[128 + j];
    const int wstride = stripes * 4;

    #pragma unroll 1
    for (int tile = s * 4 + wave; tile < ntiles; tile += wstride) {
        const int i0 = tile * 16;

        // epilogue c-children prefetch (independent; hides under K-loop)
        float clv[4], crv[4];
        int   gnrow[4];
        #pragma unroll
        for (int r = 0; r < 4; ++r) {
            int m = i0 + q * 4 + r;
            int b = m >> lc, pos = m & mask;
            int gl = b * NPT_ + child_base + 2 * pos;
            gnrow[r] = b * NPT_ + node_base + pos;
            clv[r] = c[(size_t)gl * H_ + j];
            crv[r] = c[(size_t)(gl + 1) * H_ + j];
        }

        // A: 16 h_cat rows; kt<4 left child, kt>=4 right child
        int ia = i0 + li, ba = ia >> lc, pa = ia & mask;
        int gl0 = ba * NPT_ + child_base + 2 * pa;
        const ushort_t* pl = h + (size_t)gl0 * H_;
        const ushort_t* pr = h + (size_t)(gl0 + 1) * H_;
        bf16x8 a[8];
        #pragma unroll
        for (int kt = 0; kt < 8; ++kt) {
            const ushort_t* p = (kt < 4) ? pl : pr;
            a[kt] = *(const bf16x8*)(p + (kt & 3) * 32 + q8);
        }

        f32x4 acc[5];
        #pragma unroll
        for (int t = 0; t < 5; ++t) acc[t] = (f32x4){0.f, 0.f, 0.f, 0.f};
        #pragma unroll
        for (int kt = 0; kt < 8; ++kt) {
            #pragma unroll
            for (int t = 0; t < 5; ++t) {
                bf16x8 bf = *(const bf16x8*)(Bs + (t * 16 + li) * BROW + kt * 32 + q8);
                acc[t] = __builtin_amdgcn_mfma_f32_16x16x32_bf16(a[kt], bf, acc[t], 0, 0, 0);
            }
        }

        #pragma unroll
        for (int r = 0; r < 4; ++r) {
            size_t gn = (size_t)gnrow[r] * H_ + j;
            float iv = sigmoidf_(acc[0][r] + bi);
            float ov = sigmoidf_(acc[1][r] + bo);
            float uv = tanhf_(acc[2][r] + bu);
            float fl = sigmoidf_(acc[3][r] + bfl);
            float fr = sigmoidf_(acc[4][r] + bfr);
            float cv = iv * uv + fl * clv[r] + fr * crv[r];
            float hv = ov * tanhf_(cv);
            c[gn] = cv;
            h[gn] = f2bf(hv);
        }
    }
}

// =====================================================================
// Tail — r13-verified: one block (8 waves = 8 gate groups) per TREE.
// Levels cnt=32..1 + root; tail h/c in LDS (63 nodes); c f32.
// Output head: 4-way K-parallel dot product across all 512 threads.
// =====================================================================
#define TPAD 132
__global__ __launch_bounds__(512, 2)
void tail_kernel(const ushort_t* __restrict__ Ucat,
                 const float* __restrict__ b_iou,
                 const float* __restrict__ U_f_b,
                 const ushort_t* __restrict__ h,
                 const float* __restrict__ c,
                 const float* __restrict__ W_out,
                 const float* __restrict__ b_out,
                 float* __restrict__ out) {
    __shared__ ushort_t hl[63][TPAD];
    __shared__ float    cl[63][TPAD];
    __shared__ float    ev[H_];
    __shared__ float    red[128];
    __shared__ float    red4[4][128];

    const int tid  = threadIdx.x;
    const int lane = tid & 63;
    const int wave = tid >> 6;
    const int li   = lane & 15;
    const int q    = lane >> 4;
    const int q8   = q << 3;
    const int gg   = wave;
    const int j    = gg * 16 + li;
    const int b    = blockIdx.x;

    bf16x8 Bf[5][8];
    #pragma unroll
    for (int t = 0; t < 5; ++t) {
        const ushort_t* bp = Ucat + (size_t)(16 * (gg + 8 * t) + li) * 256 + q8;
        #pragma unroll
        for (int kt = 0; kt < 8; ++kt) Bf[t][kt] = *(const bf16x8*)(bp + kt * 32);
    }

    const float bi  = b_iou[j], bo = b_iou[128 + j], bu = b_iou[256 + j];
    const float bfl = U_f_b[j], bfr = U_f_b[128 + j];

    int base = TBASE, child = 896, cnt = 32;
    #pragma unroll 1
    for (int lvl = 0; lvl < 6; ++lvl) {
        const int tiles = (cnt + 15) >> 4;
        for (int tile = 0; tile < tiles; ++tile) {
            const int i0 = tile * 16;

            int pos = i0 + li; if (pos >= cnt) pos = cnt - 1;
            bf16x8 a[8];
            if (lvl == 0) {
                int gl0 = b * NPT_ + child + 2 * pos;
                const ushort_t* pl = h + (size_t)gl0 * H_;
                const ushort_t* pr = h + (size_t)(gl0 + 1) * H_;
                #pragma unroll
                for (int kt = 0; kt < 8; ++kt) {
                    const ushort_t* p = (kt < 4) ? pl : pr;
                    a[kt] = *(const bf16x8*)(p + (kt & 3) * 32 + q8);
                }
            } else {
                int tl = (child - TBASE) + 2 * pos;
                #pragma unroll
                for (int kt = 0; kt < 8; ++kt) {
                    const ushort_t* p = (kt < 4) ? hl[tl] : hl[tl + 1];
                    a[kt] = *(const bf16x8*)(p + (kt & 3) * 32 + q8);
                }
            }

            float clv[4], crv[4];
            #pragma unroll
            for (int r = 0; r < 4; ++r) {
                int m  = i0 + q * 4 + r;
                int pm = m < cnt ? m : cnt - 1;
                if (lvl == 0) {
                    int gl = b * NPT_ + child + 2 * pm;
                    clv[r] = c[(size_t)gl * H_ + j];
                    crv[r] = c[(size_t)(gl + 1) * H_ + j];
                } else {
                    int tl = (child - TBASE) + 2 * pm;
                    clv[r] = cl[tl][j];
                    crv[r] = cl[tl + 1][j];
                }
            }

            f32x4 acc[5];
            #pragma unroll
            for (int t = 0; t < 5; ++t) acc[t] = (f32x4){0.f, 0.f, 0.f, 0.f};
            #pragma unroll
            for (int kt = 0; kt < 8; ++kt)
                #pragma unroll
                for (int t = 0; t < 5; ++t)
                    acc[t] = __builtin_amdgcn_mfma_f32_16x16x32_bf16(a[kt], Bf[t][kt], acc[t], 0, 0, 0);

            #pragma unroll
            for (int r = 0; r < 4; ++r) {
                int m = i0 + q * 4 + r;
                if (m < cnt) {
                    int tl = (base - TBASE) + m;
                    float iv = sigmoidf_(acc[0][r] + bi);
                    float ov = sigmoidf_(acc[1][r] + bo);
                    float uv = tanhf_(acc[2][r] + bu);
                    float fl = sigmoidf_(acc[3][r] + bfl);
                    float fr = sigmoidf_(acc[4][r] + bfr);
                    float cv = iv * uv + fl * clv[r] + fr * crv[r];
                    float hv = ov * tanhf_(cv);
                    cl[tl][j] = cv;
                    hl[tl][j] = f2bf(hv);
                }
            }
        }
        __syncthreads();
        child = base; base += cnt; cnt >>= 1;
    }

    if (tid < 128) ev[tid] = bf2f(hl[62][tid]);
    __syncthreads();

    // ---- output head: out[o] = b_out[o] + sum_k ev[k]*W_out[k][o] ----
    {
        const int o  = tid & 127;
        const int kc = tid >> 7;            // 0..3 -> k in [kc*32, kc*32+32)
        float pacc = (kc == 0) ? b_out[o] : 0.0f;
        #pragma unroll 8
        for (int k = kc * 32; k < kc * 32 + 32; ++k)
            pacc += ev[k] * W_out[k * OUT_ + o];
        red4[kc][o] = pacc;
    }
    __syncthreads();

    float acc = 0.0f;
    if (tid < 128) {
        acc = red4[0][tid] + red4[1][tid] + red4[2][tid] + red4[3][tid];
        red[tid] = acc;
    }
    __syncthreads();
    for (int s = 64; s > 0; s >>= 1) {
        if (tid < s) red[tid] = fmaxf(red[tid], red[tid + s]);
        __syncthreads();
    }
    float mx = red[0];
    __syncthreads();
    if (tid < 128) red[tid] = expf(acc - mx);
    __syncthreads();
    for (int s = 64; s > 0; s >>= 1) {
        if (tid < s) red[tid] += red[tid + s];
        __syncthreads();
    }
    float lse = logf(red[0]);
    if (tid < 128) out[b * OUT_ + tid] = acc - mx - lse;
}

// =====================================================================
extern "C" void kernel_launch(void* const* d_in, const int* in_sizes, int n_in,
                              void* d_out, int out_size, void* d_ws, size_t ws_size,
                              hipStream_t stream) {
    const int*   label = (const int*)d_in[0];
    const float* emb   = (const float*)d_in[1];
    const float* W_iou = (const float*)d_in[2];
    const float* U_iou = (const float*)d_in[3];
    const float* b_iou = (const float*)d_in[4];
    const float* U_f_w = (const float*)d_in[5];
    const float* U_f_b = (const float*)d_in[6];
    const float* W_out = (const float*)d_in[7];
    const float* b_out = (const float*)d_in[8];
    float* outp = (float*)d_out;

    // ws layout: c f32 | h bf16 | Ucat | WT | embb
    float*    c    = (float*)d_ws;
    ushort_t* h    = (ushort_t*)(c + (size_t)N_ * H_);
    ushort_t* Ucat = h + (size_t)N_ * H_;
    ushort_t* WT   = Ucat + 640 * 256;
    ushort_t* embb = WT + 384 * 128;

    prep_fused<<<2000, 256, 0, stream>>>(W_iou, U_iou, U_f_w, emb, WT, Ucat, embb);

    // leaf: 4096 M-tiles of 16; 512 stripes x 2 group-halves; 8 tiles/wave
    leaf_v3<<<dim3(512, 2), 256, 0, stream>>>(label, embb, WT, b_iou, h, c);

    // big levels: cnt = 256,128,64 — r2 structure + XCD-swizzled 1-D grid
    // (8 gg-blocks of a stripe adjacent AND same-XCD: x = 64*chunk+8*gg+r)
    int child = 0, node = 512, cnt = 256, lc = 8;
    for (int lvl = 0; lvl < 3; ++lvl) {
        int ntiles  = (B_ * cnt) / 16;
        int stripes = ntiles / 16;          // 4 waves x 4 tiles per block
        level_lds<<<stripes * 8, 256, 0, stream>>>(
            Ucat, b_iou, U_f_b, h, c, node, child, lc, ntiles);
        child = node; node += cnt; cnt >>= 1; --lc;
    }

    // tail: cnt=32..1 + root, one block per tree
    tail_kernel<<<B_, 512, 0, stream>>>(Ucat, b_iou, U_f_b, h, c, W_out, b_out, outp);
}